// Round 4
// baseline (492.701 us; speedup 1.0000x reference)
//
#include <hip/hip_runtime.h>
#include <math.h>
#include <stdint.h>

#define NB      65536
#define LIN     274
#define SEQ     18
#define DM      16
#define NH      4
#define HID     64
#define NLAYER  4
#define EPSF    1e-5f

// ---- MFMA-path config ----
#define EPB      8                 // batch elements per block
#define NTHREADS 192               // 3 waves; 144 tokens = 9 row-tiles of 16
// LDS: two K/V buffers of 3488 dwords each:
//   K  f16x4 [e*4+h][s]            : 1152 dw
//   V  f32   [e][s][d] stride 292  : 2336 dw  (292 % 32 = 4 -> bank stagger)
// x staging (2192 dw) aliases buffer 1.
#define BUF_DW   3488
#define VOFF_DW  1152
#define VSTR     292
#define SMEM_DW  (2 * BUF_DW)

#define QS 0.72134752044448170f    // (1/sqrt(DH)) * log2(e)

typedef _Float16 h2    __attribute__((ext_vector_type(2)));
typedef _Float16 f16x4 __attribute__((ext_vector_type(4)));
typedef _Float16 f16x8 __attribute__((ext_vector_type(8)));
typedef float    f32x4 __attribute__((ext_vector_type(4)));
typedef __fp16   hf2_raw __attribute__((ext_vector_type(2)));

#if __has_builtin(__builtin_amdgcn_fdot2)
__device__ __forceinline__ float fdot2(h2 a, h2 b, float c) { return __builtin_amdgcn_fdot2(a, b, c, false); }
#else
__device__ __forceinline__ float fdot2(h2 a, h2 b, float c) { return c + (float)a[0] * (float)b[0] + (float)a[1] * (float)b[1]; }
#endif
#if __has_builtin(__builtin_amdgcn_cvt_pkrtz)
__device__ __forceinline__ h2 pkrtz(float a, float b) {
    hf2_raw r = __builtin_amdgcn_cvt_pkrtz(a, b);
    return __builtin_bit_cast(h2, r);
}
#else
__device__ __forceinline__ h2 pkrtz(float a, float b) { h2 r; r[0] = (_Float16)a; r[1] = (_Float16)b; return r; }
#endif

#if __has_builtin(__builtin_amdgcn_mfma_f32_16x16x16f16)
__device__ __forceinline__ f32x4 MFMA16(f16x4 a, f16x4 b, f32x4 c) {
    return __builtin_amdgcn_mfma_f32_16x16x16f16(a, b, c, 0, 0, 0);
}
#elif __has_builtin(__builtin_amdgcn_mfma_f32_16x16x16_f16)
__device__ __forceinline__ f32x4 MFMA16(f16x4 a, f16x4 b, f32x4 c) {
    return __builtin_amdgcn_mfma_f32_16x16x16_f16(a, b, c, 0, 0, 0);
}
#else
__device__ __forceinline__ f32x4 MFMA16(f16x4 a, f16x4 b, f32x4 c) {
    f32x4 d;
    asm volatile("v_mfma_f32_16x16x16_f16 %0, %1, %2, %3"
                 : "=v"(d) : "v"(a), "v"(b), "v"(c));
    return d;
}
#endif

__device__ __forceinline__ float fast_rcp(float x)  { return __builtin_amdgcn_rcpf(x); }
__device__ __forceinline__ float fast_rsq(float x)  { return __builtin_amdgcn_rsqf(x); }
__device__ __forceinline__ float fast_exp2(float x) { return __builtin_amdgcn_exp2f(x); }

// butterfly sum over lanes {l, l^16, l^32, l^48} — VALU permlane on gfx950, no LDS
__device__ __forceinline__ float bfly16_32(float x) {
#if __has_builtin(__builtin_amdgcn_permlane16_swap) && __has_builtin(__builtin_amdgcn_permlane32_swap)
    unsigned u = __builtin_bit_cast(unsigned, x);
    auto p16 = __builtin_amdgcn_permlane16_swap(u, u, false, false);
    float s = __builtin_bit_cast(float, (unsigned)p16[0]) + __builtin_bit_cast(float, (unsigned)p16[1]);
    unsigned v = __builtin_bit_cast(unsigned, s);
    auto p32 = __builtin_amdgcn_permlane32_swap(v, v, false, false);
    return __builtin_bit_cast(float, (unsigned)p32[0]) + __builtin_bit_cast(float, (unsigned)p32[1]);
#else
    x += __shfl_xor(x, 16);
    x += __shfl_xor(x, 32);
    return x;
#endif
}

// gelu(t) ~= t * sigmoid(2 * t * (A + B t^2)); 2*log2(e) pre-folded into A,B
__device__ __forceinline__ float gelu_tanh(float t) {
    const float A2 = 0.79788456080286536f * 2.88539008177792681f;
    const float B2 = 0.03567740814183430f * 2.88539008177792681f;
    float u  = t * fmaf(t * t, B2, A2);
    float e  = fast_exp2(u);
    float r  = fast_rcp(e + 1.0f);
    return fmaf(-t, r, t);
}

__device__ __forceinline__ f16x4 pk4(float a, float b, float c, float d) {
    h2 lo = pkrtz(a, b), hi = pkrtz(c, d);
    f16x4 r; r[0] = lo[0]; r[1] = lo[1]; r[2] = hi[0]; r[3] = hi[1];
    return r;
}
__device__ __forceinline__ f32x4 ld4(const float* p) {
    float4 t = *(const float4*)p;
    f32x4 r; r[0] = t.x; r[1] = t.y; r[2] = t.z; r[3] = t.w;
    return r;
}
__device__ __forceinline__ h2 h2at(f16x8 v, int i) {   // i compile-time, 0..3
    h2 r; r[0] = v[2 * i]; r[1] = v[2 * i + 1]; return r;
}

// ---- workspace layout ----
// [0, 6400) h2  : 50 weight tiles of 64 lanes x 2 h2 (A-fragment, lane = A[row=l&15][k=(l>>4)*4+i])
//   tile 0 patchify, tile 1 decoder; per layer li (base 2+li*12):
//   j=0..2 qkv (q-tile pre-scaled by QS; qkv & w1 cols pre-scaled by LN gain)
//   j=3 out_w ; j=4..7 w1 ; j=8..11 w2
// [6400 h2 ..) f32: per layer 112 floats: 48 folded qkv bias, 64 folded w1 bias
#define WS_H2_COUNT 6400
#define WS_BIAS_FLOATS (NLAYER * 112)
#define WS_TOTAL_BYTES (WS_H2_COUNT * 4 + WS_BIAS_FLOATS * 4)
#define PREP_ITEMS (WS_H2_COUNT + WS_BIAS_FLOATS)

__global__ __launch_bounds__(512) void prep_weights(
    const float* __restrict__ patch_w, const float* __restrict__ dec_w,
    const float* __restrict__ qkv_w, const float* __restrict__ out_w,
    const float* __restrict__ mlp_w1, const float* __restrict__ mlp_w2,
    const float* __restrict__ ln1_g, const float* __restrict__ ln1_b,
    const float* __restrict__ ln2_g, const float* __restrict__ ln2_b,
    const float* __restrict__ qkv_b, const float* __restrict__ mlp_b1,
    h2* __restrict__ ws)
{
    int i = blockIdx.x * 512 + threadIdx.x;
    if (i >= PREP_ITEMS) return;
    if (i < WS_H2_COUNT) {
        int tile = i >> 7;
        int lane = (i >> 1) & 63;
        int p    = i & 1;
        int row  = lane & 15;
        int kb   = (lane >> 4) * 4 + 2 * p;
        float a, b;
        if (tile == 0)      { a = patch_w[row * 16 + kb];  b = patch_w[row * 16 + kb + 1]; }
        else if (tile == 1) { a = dec_w[kb * 16 + row];    b = dec_w[(kb + 1) * 16 + row]; }
        else {
            int t2 = tile - 2, li = t2 / 12, j = t2 % 12;
            const float* s;
            float g0 = 1.0f, g1v = 1.0f;
            if (j < 3) {
                s = qkv_w + li * 768 + (j * 16 + row) * 16 + kb;
                g0 = ln1_g[li * 16 + kb]; g1v = ln1_g[li * 16 + kb + 1];
                if (j == 0) { g0 *= QS; g1v *= QS; }
            } else if (j == 3) {
                s = out_w + li * 256 + row * 16 + kb;
            } else if (j < 8) {
                s = mlp_w1 + li * 1024 + ((j - 4) * 16 + row) * 16 + kb;
                g0 = ln2_g[li * 16 + kb]; g1v = ln2_g[li * 16 + kb + 1];
            } else {
                s = mlp_w2 + li * 1024 + row * 64 + (j - 8) * 16 + kb;
            }
            a = s[0] * g0; b = s[1] * g1v;
        }
        ws[i] = pkrtz(a, b);
    } else {
        int t = i - WS_H2_COUNT;
        int li = t / 112, r = t % 112;
        float* wbf = (float*)(ws + WS_H2_COUNT);
        float bv;
        if (r < 48) {
            const float* Wr = qkv_w + li * 768 + r * 16;
            const float* lb = ln1_b + li * 16;
            bv = qkv_b[li * 48 + r];
            for (int d = 0; d < 16; ++d) bv = fmaf(Wr[d], lb[d], bv);
            if (r < 16) bv *= QS;
        } else {
            int j = r - 48;
            const float* Wr = mlp_w1 + li * 1024 + j * 16;
            const float* lb = ln2_b + li * 16;
            bv = mlp_b1[li * 64 + j];
            for (int d = 0; d < 16; ++d) bv = fmaf(Wr[d], lb[d], bv);
        }
        wbf[li * 112 + r] = bv;
    }
}

__global__ __launch_bounds__(NTHREADS) void ae_fwd(
    const float* __restrict__ x,
    const float* __restrict__ patch_b, const float* __restrict__ pos_embed,
    const h2*    __restrict__ wp, const float* __restrict__ wb,
    const float* __restrict__ out_b, const float* __restrict__ mlp_b2,
    const float* __restrict__ lnf_g, const float* __restrict__ lnf_b,
    const float* __restrict__ dec_b,
    float* __restrict__ out_y, float* __restrict__ out_z)
{
    __shared__ float smem[SMEM_DW];
    const int tid  = threadIdx.x;
    const int lane = tid & 63;
    const int wv   = tid >> 6;       // 0..2
    const int col  = lane & 15;      // token-within-tile (MFMA col)
    const int g16  = lane >> 4;      // 0..3: k-group AND head index
    const int fb   = g16 * 4;        // this lane's feature base

    // ---- stage x (coalesced float4) into buffer-1 region ----
    {
        const float4* xg = (const float4*)(x + (long long)blockIdx.x * (EPB * LIN));
        float4* xs = (float4*)(smem + BUF_DW);
        for (int i = tid; i < (EPB * LIN) / 4; i += NTHREADS) xs[i] = xg[i];
    }
    __syncthreads();

    // ---- per-tile token -> (element, seq) ----
    int elemL[3], sIdx[3];
    #pragma unroll
    for (int t = 0; t < 3; ++t) {
        int T = wv * 48 + t * 16 + col;      // 0..143
        int e = (T * 57) >> 10;              // floor(T/18), exact for T<504
        elemL[t] = e;
        sIdx[t]  = T - 18 * e;
    }

    const f16x4* wfrag = (const f16x4*)wp;
    const f16x4 wpatch = wfrag[lane];
    const f16x4 wdec   = wfrag[64 + lane];

    // ---- patchify via MFMA (reads x from buffer-1 region) ----
    float hacc[3][4];
    {
        const float4 pb = *(const float4*)(patch_b + fb);
        const float* xst = smem + BUF_DW;
        #pragma unroll
        for (int t = 0; t < 3; ++t) {
            float xv[4];
            #pragma unroll
            for (int r = 0; r < 4; ++r) {
                int loc = sIdx[t] * 16 - 7 + fb + r;
                xv[r] = (loc >= 0 && loc < LIN) ? xst[elemL[t] * LIN + loc] : 0.0f;
            }
            f16x4 xb = pk4(xv[0], xv[1], xv[2], xv[3]);
            const float4 pe = *(const float4*)(pos_embed + sIdx[t] * DM + fb);
            f32x4 c; c[0] = pb.x + pe.x; c[1] = pb.y + pe.y; c[2] = pb.z + pe.z; c[3] = pb.w + pe.w;
            c = MFMA16(wpatch, xb, c);
            #pragma unroll
            for (int r = 0; r < 4; ++r) hacc[t][r] = c[r];
        }
    }

    #pragma unroll 1
    for (int li = 0; li < NLAYER; ++li) {
        const int bufO = (li & 1) ? BUF_DW : 0;
        const f16x4* wl = wfrag + (2 + li * 12) * 64 + lane;
        const float* wbL = wb + li * 112;
        const f32x4 bq = ld4(wbL + fb);
        const f32x4 bk = ld4(wbL + 16 + fb);
        const f32x4 bvx = ld4(wbL + 32 + fb);
        f32x4 b1r[4];
        #pragma unroll
        for (int c = 0; c < 4; ++c) b1r[c] = ld4(wbL + 48 + c * 16 + fb);
        const float4 ob4 = *(const float4*)(out_b + li * DM + fb);
        const f32x4 b2r = ld4(mlp_b2 + li * DM + fb);

        // ---- LN1 (affine folded into weights) + QKV ----
        h2 qp[3][2]; f16x4 kpk[3]; f32x4 vreg[3];
        #pragma unroll
        for (int t = 0; t < 3; ++t) {
            float a0 = hacc[t][0], a1 = hacc[t][1], a2 = hacc[t][2], a3 = hacc[t][3];
            float sm = bfly16_32(a0 + a1 + a2 + a3);
            float qq = bfly16_32(fmaf(a0, a0, fmaf(a1, a1, fmaf(a2, a2, a3 * a3))));
            float mean = sm * (1.0f / 16.0f);
            float var  = fmaxf(fmaf(mean, -mean, qq * (1.0f / 16.0f)), 0.0f);
            float inv  = fast_rsq(var + EPSF);
            float mi   = mean * inv;
            f16x4 xb = pk4(fmaf(a0, inv, -mi), fmaf(a1, inv, -mi),
                           fmaf(a2, inv, -mi), fmaf(a3, inv, -mi));
            f32x4 aq = MFMA16(wl[0],   xb, bq);
            f32x4 ak = MFMA16(wl[64],  xb, bk);
            f32x4 av = MFMA16(wl[128], xb, bvx);
            qp[t][0] = pkrtz(aq[0], aq[1]);
            qp[t][1] = pkrtz(aq[2], aq[3]);
            kpk[t] = pk4(ak[0], ak[1], ak[2], ak[3]);
            vreg[t] = av;
        }
        // double-buffered: no pre-write barrier needed
        #pragma unroll
        for (int t = 0; t < 3; ++t) {
            ((f16x4*)(smem + bufO))[(elemL[t] * 4 + g16) * 18 + sIdx[t]] = kpk[t];
            float4 vv; vv.x = vreg[t][0]; vv.y = vreg[t][1]; vv.z = vreg[t][2]; vv.w = vreg[t][3];
            *(float4*)(smem + bufO + VOFF_DW + elemL[t] * VSTR + sIdx[t] * 16 + g16 * 4) = vv;
        }
        __syncthreads();   // K/V visible

        // ---- attention (softmax lane-local) + out-proj ----
        #pragma unroll
        for (int t = 0; t < 3; ++t) {
            const int e = elemL[t];
            const f16x4* Kb = (const f16x4*)(smem + bufO) + (e * 4 + g16) * 18;
            float sc[SEQ]; float ssum = 0.0f;
            #pragma unroll
            for (int jp = 0; jp < 9; ++jp) {
                f16x8 k2 = *(const f16x8*)(Kb + 2 * jp);
                float s0 = fdot2(qp[t][1], h2at(k2, 1), fdot2(qp[t][0], h2at(k2, 0), 0.0f));
                float s1 = fdot2(qp[t][1], h2at(k2, 3), fdot2(qp[t][0], h2at(k2, 2), 0.0f));
                float w0 = fast_exp2(s0), w1 = fast_exp2(s1);
                sc[2 * jp] = w0; sc[2 * jp + 1] = w1;
                ssum += w0 + w1;
            }
            float inv = fast_rcp(ssum);
            const float* vb = smem + bufO + VOFF_DW + e * VSTR + g16 * 4;
            float o0 = 0.f, o1 = 0.f, o2 = 0.f, o3 = 0.f;
            #pragma unroll
            for (int j = 0; j < SEQ; ++j) {
                float4 vj = *(const float4*)(vb + j * 16);
                float w = sc[j];
                o0 = fmaf(w, vj.x, o0); o1 = fmaf(w, vj.y, o1);
                o2 = fmaf(w, vj.z, o2); o3 = fmaf(w, vj.w, o3);
            }
            f16x4 obf = pk4(o0 * inv, o1 * inv, o2 * inv, o3 * inv);
            f32x4 oa; oa[0] = ob4.x; oa[1] = ob4.y; oa[2] = ob4.z; oa[3] = ob4.w;
            oa = MFMA16(wl[192], obf, oa);
            #pragma unroll
            for (int r = 0; r < 4; ++r) hacc[t][r] += oa[r];
        }

        // ---- LN2 (affine folded) + MLP ----
        #pragma unroll
        for (int t = 0; t < 3; ++t) {
            float a0 = hacc[t][0], a1 = hacc[t][1], a2 = hacc[t][2], a3 = hacc[t][3];
            float sm = bfly16_32(a0 + a1 + a2 + a3);
            float qq = bfly16_32(fmaf(a0, a0, fmaf(a1, a1, fmaf(a2, a2, a3 * a3))));
            float mean = sm * (1.0f / 16.0f);
            float var  = fmaxf(fmaf(mean, -mean, qq * (1.0f / 16.0f)), 0.0f);
            float inv  = fast_rsq(var + EPSF);
            float mi   = mean * inv;
            f16x4 xb2 = pk4(fmaf(a0, inv, -mi), fmaf(a1, inv, -mi),
                            fmaf(a2, inv, -mi), fmaf(a3, inv, -mi));
            f32x4 acc2 = b2r;
            #pragma unroll
            for (int c = 0; c < 4; ++c) {
                f32x4 m1 = MFMA16(wl[(4 + c) * 64], xb2, b1r[c]);
                f16x4 gb = pk4(gelu_tanh(m1[0]), gelu_tanh(m1[1]),
                               gelu_tanh(m1[2]), gelu_tanh(m1[3]));
                acc2 = MFMA16(wl[(8 + c) * 64], gb, acc2);
            }
            #pragma unroll
            for (int r = 0; r < 4; ++r) hacc[t][r] += acc2[r];
        }
    }

    // ---- final LN + z + decoder (MFMA) + y ----
    const float4 gf = *(const float4*)(lnf_g + fb);
    const float4 bf = *(const float4*)(lnf_b + fb);
    const float db0 = dec_b[0];
    #pragma unroll
    for (int t = 0; t < 3; ++t) {
        float a0 = hacc[t][0], a1 = hacc[t][1], a2 = hacc[t][2], a3 = hacc[t][3];
        float sm = bfly16_32(a0 + a1 + a2 + a3);
        float qq = bfly16_32(fmaf(a0, a0, fmaf(a1, a1, fmaf(a2, a2, a3 * a3))));
        float mean = sm * (1.0f / 16.0f);
        float var  = fmaxf(fmaf(mean, -mean, qq * (1.0f / 16.0f)), 0.0f);
        float inv  = fast_rsq(var + EPSF);
        float mi   = mean * inv;
        float f0 = fmaf(fmaf(a0, inv, -mi), gf.x, bf.x);
        float f1 = fmaf(fmaf(a1, inv, -mi), gf.y, bf.y);
        float f2 = fmaf(fmaf(a2, inv, -mi), gf.z, bf.z);
        float f3 = fmaf(fmaf(a3, inv, -mi), gf.w, bf.w);

        long long eg = (long long)blockIdx.x * EPB + elemL[t];
        float* zb = out_z + eg * (DM * SEQ) + sIdx[t];
        zb[(fb + 0) * SEQ] = f0; zb[(fb + 1) * SEQ] = f1;
        zb[(fb + 2) * SEQ] = f2; zb[(fb + 3) * SEQ] = f3;

        f16x4 hb = pk4(f0, f1, f2, f3);
        f32x4 y4; y4[0] = db0; y4[1] = db0; y4[2] = db0; y4[3] = db0;
        y4 = MFMA16(wdec, hb, y4);
        float* yb = out_y + eg * LIN;
        int p0 = sIdx[t] * 16 + fb - 7;
        #pragma unroll
        for (int r = 0; r < 4; ++r) {
            int p = p0 + r;
            if (p >= 0 && p < LIN) yb[p] = y4[r];
        }
    }
}

// ---------------- fp32 fallback (used only if ws_size is too small) ----------------
#define EPB_F 14
#define NT_F  252
__global__ __launch_bounds__(NT_F) void ae_fwd_f32(
    const float* __restrict__ x,
    const float* __restrict__ patch_w, const float* __restrict__ patch_b,
    const float* __restrict__ pos_embed,
    const float* __restrict__ ln1_g, const float* __restrict__ ln1_b,
    const float* __restrict__ qkv_w, const float* __restrict__ qkv_b,
    const float* __restrict__ out_w, const float* __restrict__ out_b,
    const float* __restrict__ ln2_g, const float* __restrict__ ln2_b,
    const float* __restrict__ mlp_w1, const float* __restrict__ mlp_b1,
    const float* __restrict__ mlp_w2, const float* __restrict__ mlp_b2,
    const float* __restrict__ lnf_g, const float* __restrict__ lnf_b,
    const float* __restrict__ dec_w, const float* __restrict__ dec_b,
    float* __restrict__ out_y, float* __restrict__ out_z)
{
    __shared__ float s_kv[EPB_F * 580];
    const int tid = threadIdx.x;
    const int e   = tid / SEQ;
    const int s   = tid - e * SEQ;
    const long long b = (long long)blockIdx.x * EPB_F + e;
    const bool valid = (b < NB);
    {
        const long long base = (long long)blockIdx.x * (EPB_F * LIN);
        const long long lim  = (long long)NB * LIN - 1;
        for (int i = tid; i < EPB_F * LIN; i += NT_F) {
            long long gi = base + i;
            if (gi > lim) gi = lim;
            s_kv[i] = x[gi];
        }
    }
    __syncthreads();
    float xv[16];
    {
        const float* xe = &s_kv[e * LIN];
        #pragma unroll
        for (int k = 0; k < 16; ++k) {
            int idx = s * 16 - 7 + k;
            xv[k] = (idx >= 0 && idx < LIN) ? xe[idx] : 0.0f;
        }
    }
    float h[DM];
    #pragma unroll
    for (int d = 0; d < DM; ++d) {
        float acc = patch_b[d] + pos_embed[s * DM + d];
        #pragma unroll
        for (int k = 0; k < 16; ++k) acc = fmaf(xv[k], patch_w[d * 16 + k], acc);
        h[d] = acc;
    }
    #pragma unroll 1
    for (int li = 0; li < NLAYER; ++li) {
        float xn[DM];
        {
            float m = 0.f;
            #pragma unroll
            for (int d = 0; d < DM; ++d) m += h[d];
            m *= (1.0f / DM);
            float v = 0.f;
            #pragma unroll
            for (int d = 0; d < DM; ++d) { float t = h[d] - m; v = fmaf(t, t, v); }
            v *= (1.0f / DM);
            float inv = fast_rsq(v + EPSF);
            #pragma unroll
            for (int d = 0; d < DM; ++d) xn[d] = (h[d] - m) * inv * ln1_g[li * DM + d] + ln1_b[li * DM + d];
        }
        float q[DM], kk[DM], vv[DM];
        {
            const float* W  = qkv_w + li * 48 * DM;
            const float* Wb = qkv_b + li * 48;
            #pragma unroll
            for (int j = 0; j < DM; ++j) {
                float aq = Wb[j], ak = Wb[DM + j], av = Wb[2 * DM + j];
                #pragma unroll
                for (int d = 0; d < DM; ++d) {
                    float xd = xn[d];
                    aq = fmaf(xd, W[j * DM + d], aq);
                    ak = fmaf(xd, W[(DM + j) * DM + d], ak);
                    av = fmaf(xd, W[(2 * DM + j) * DM + d], av);
                }
                q[j] = aq; kk[j] = ak; vv[j] = av;
            }
        }
        __syncthreads();
        {
            float* kb = &s_kv[e * 580];
            float* vb = kb + SEQ * DM;
            #pragma unroll
            for (int j = 0; j < DM; ++j) kb[s * DM + j] = kk[j];
            #pragma unroll
            for (int j = 0; j < DM; ++j) vb[s * DM + j] = vv[j];
        }
        __syncthreads();
        float o[DM];
        {
            const float* kb = &s_kv[e * 580];
            const float* vb = kb + SEQ * DM;
            #pragma unroll
            for (int hh = 0; hh < NH; ++hh) {
                const float qscale = 0.5f * 1.44269504088896341f;
                const float q0 = q[hh * 4] * qscale, q1 = q[hh * 4 + 1] * qscale;
                const float q2 = q[hh * 4 + 2] * qscale, q3 = q[hh * 4 + 3] * qscale;
                float sc[SEQ];
                float ssum = 0.f;
                #pragma unroll
                for (int j = 0; j < SEQ; ++j) {
                    const float4 kj = *(const float4*)(kb + j * DM + hh * 4);
                    float t = fmaf(q0, kj.x, fmaf(q1, kj.y, fmaf(q2, kj.z, q3 * kj.w)));
                    float w = fast_exp2(t);
                    sc[j] = w; ssum += w;
                }
                const float inv = fast_rcp(ssum);
                float a0 = 0.f, a1 = 0.f, a2 = 0.f, a3 = 0.f;
                #pragma unroll
                for (int j = 0; j < SEQ; ++j) {
                    const float4 vj = *(const float4*)(vb + j * DM + hh * 4);
                    const float w = sc[j] * inv;
                    a0 = fmaf(w, vj.x, a0); a1 = fmaf(w, vj.y, a1);
                    a2 = fmaf(w, vj.z, a2); a3 = fmaf(w, vj.w, a3);
                }
                o[hh * 4] = a0; o[hh * 4 + 1] = a1; o[hh * 4 + 2] = a2; o[hh * 4 + 3] = a3;
            }
        }
        {
            const float* W  = out_w + li * DM * DM;
            #pragma unroll
            for (int d = 0; d < DM; ++d) {
                float acc = out_b[li * DM + d];
                #pragma unroll
                for (int d2 = 0; d2 < DM; ++d2) acc = fmaf(o[d2], W[d * DM + d2], acc);
                h[d] += acc;
            }
        }
        float xn2[DM];
        {
            float m = 0.f;
            #pragma unroll
            for (int d = 0; d < DM; ++d) m += h[d];
            m *= (1.0f / DM);
            float v = 0.f;
            #pragma unroll
            for (int d = 0; d < DM; ++d) { float t = h[d] - m; v = fmaf(t, t, v); }
            v *= (1.0f / DM);
            float inv = fast_rsq(v + EPSF);
            #pragma unroll
            for (int d = 0; d < DM; ++d) xn2[d] = (h[d] - m) * inv * ln2_g[li * DM + d] + ln2_b[li * DM + d];
        }
        {
            const float* W1 = mlp_w1 + li * HID * DM;
            const float* W2 = mlp_w2 + li * DM * HID;
            float acc2[DM];
            #pragma unroll
            for (int d = 0; d < DM; ++d) acc2[d] = mlp_b2[li * DM + d];
            #pragma unroll 2
            for (int j = 0; j < HID; ++j) {
                float t = mlp_b1[li * HID + j];
                #pragma unroll
                for (int d = 0; d < DM; ++d) t = fmaf(xn2[d], W1[j * DM + d], t);
                float g = gelu_tanh(t);
                #pragma unroll
                for (int d = 0; d < DM; ++d) acc2[d] = fmaf(g, W2[d * HID + j], acc2[d]);
            }
            #pragma unroll
            for (int d = 0; d < DM; ++d) h[d] += acc2[d];
        }
    }
    {
        float m = 0.f;
        #pragma unroll
        for (int d = 0; d < DM; ++d) m += h[d];
        m *= (1.0f / DM);
        float v = 0.f;
        #pragma unroll
        for (int d = 0; d < DM; ++d) { float t = h[d] - m; v = fmaf(t, t, v); }
        v *= (1.0f / DM);
        float inv = fast_rsq(v + EPSF);
        #pragma unroll
        for (int d = 0; d < DM; ++d) h[d] = (h[d] - m) * inv * lnf_g[d] + lnf_b[d];
    }
    if (valid) {
        float* zb = out_z + b * (DM * SEQ);
        #pragma unroll
        for (int d = 0; d < DM; ++d) zb[d * SEQ + s] = h[d];
        float* yb = out_y + b * LIN;
        const float db0 = dec_b[0];
        #pragma unroll
        for (int k = 0; k < 16; ++k) {
            int t = s * 16 + k - 7;
            if (t >= 0 && t < LIN) {
                float acc = db0;
                #pragma unroll
                for (int d = 0; d < DM; ++d) acc = fmaf(h[d], dec_w[d * 16 + k], acc);
                yb[t] = acc;
            }
        }
    }
}

extern "C" void kernel_launch(void* const* d_in, const int* in_sizes, int n_in,
                              void* d_out, int out_size, void* d_ws, size_t ws_size,
                              hipStream_t stream) {
    const float* x        = (const float*)d_in[0];
    const float* patch_w  = (const float*)d_in[1];
    const float* patch_b  = (const float*)d_in[2];
    const float* pos_e    = (const float*)d_in[3];
    const float* ln1_g    = (const float*)d_in[4];
    const float* ln1_b    = (const float*)d_in[5];
    const float* qkv_w    = (const float*)d_in[6];
    const float* qkv_b    = (const float*)d_in[7];
    const float* out_w    = (const float*)d_in[8];
    const float* out_b    = (const float*)d_in[9];
    const float* ln2_g    = (const float*)d_in[10];
    const float* ln2_b    = (const float*)d_in[11];
    const float* mlp_w1   = (const float*)d_in[12];
    const float* mlp_b1   = (const float*)d_in[13];
    const float* mlp_w2   = (const float*)d_in[14];
    const float* mlp_b2   = (const float*)d_in[15];
    const float* lnf_g    = (const float*)d_in[16];
    const float* lnf_b    = (const float*)d_in[17];
    const float* dec_w    = (const float*)d_in[18];
    const float* dec_b    = (const float*)d_in[19];

    float* out_y = (float*)d_out;                       // (B,1,274) first
    float* out_z = out_y + (long long)NB * LIN;         // then (B,16,18)

    if (ws_size >= WS_TOTAL_BYTES) {
        h2* wsp = (h2*)d_ws;
        const float* wbp = (const float*)(wsp + WS_H2_COUNT);
        prep_weights<<<(PREP_ITEMS + 511) / 512, 512, 0, stream>>>(
            patch_w, dec_w, qkv_w, out_w, mlp_w1, mlp_w2,
            ln1_g, ln1_b, ln2_g, ln2_b, qkv_b, mlp_b1, wsp);
        ae_fwd<<<NB / EPB, NTHREADS, 0, stream>>>(
            x, patch_b, pos_e, wsp, wbp,
            out_b, mlp_b2, lnf_g, lnf_b, dec_b, out_y, out_z);
    } else {
        const int grid = (NB + EPB_F - 1) / EPB_F;
        ae_fwd_f32<<<grid, NT_F, 0, stream>>>(
            x, patch_w, patch_b, pos_e, ln1_g, ln1_b, qkv_w, qkv_b,
            out_w, out_b, ln2_g, ln2_b, mlp_w1, mlp_b1, mlp_w2, mlp_b2,
            lnf_g, lnf_b, dec_w, dec_b, out_y, out_z);
    }
}

// Round 5
// 460.300 us; speedup vs baseline: 1.0704x; 1.0704x over previous
//
#include <hip/hip_runtime.h>
#include <math.h>
#include <stdint.h>

#define NB      65536
#define LIN     274
#define SEQ     18
#define DM      16
#define NH      4
#define HID     64
#define NLAYER  4
#define EPSF    1e-5f

// ---- MFMA-path config: 1 wave per block, zero barriers ----
#define EPB      8                 // batch elements per block (owned by ONE wave)
#define NTHREADS 64                // 144 tokens = 9 row-tiles of 16, all in one wave
// LDS (single buffer, wave-private):
//   K  f16x4 rows [e*4+h] stride 36 dw, entry s*2        : 1152 dw
//   V  f16x4 per token, stride 10 dw (addr = 10*(18e+s)+2h): 1440 dw
// x staging (2192 dw) aliases the whole region (read before first K/V write).
#define VOFF_DW  1152
#define SMEM_DW  2592

#define QS 0.72134752044448170f    // (1/sqrt(DH)) * log2(e)

typedef _Float16 h2    __attribute__((ext_vector_type(2)));
typedef _Float16 f16x4 __attribute__((ext_vector_type(4)));
typedef _Float16 f16x8 __attribute__((ext_vector_type(8)));
typedef float    f32x4 __attribute__((ext_vector_type(4)));
typedef __fp16   hf2_raw __attribute__((ext_vector_type(2)));

#if __has_builtin(__builtin_amdgcn_fdot2)
__device__ __forceinline__ float fdot2(h2 a, h2 b, float c) { return __builtin_amdgcn_fdot2(a, b, c, false); }
#else
__device__ __forceinline__ float fdot2(h2 a, h2 b, float c) { return c + (float)a[0] * (float)b[0] + (float)a[1] * (float)b[1]; }
#endif
#if __has_builtin(__builtin_amdgcn_cvt_pkrtz)
__device__ __forceinline__ h2 pkrtz(float a, float b) {
    hf2_raw r = __builtin_amdgcn_cvt_pkrtz(a, b);
    return __builtin_bit_cast(h2, r);
}
#else
__device__ __forceinline__ h2 pkrtz(float a, float b) { h2 r; r[0] = (_Float16)a; r[1] = (_Float16)b; return r; }
#endif

#if __has_builtin(__builtin_amdgcn_mfma_f32_16x16x16f16)
__device__ __forceinline__ f32x4 MFMA16(f16x4 a, f16x4 b, f32x4 c) {
    return __builtin_amdgcn_mfma_f32_16x16x16f16(a, b, c, 0, 0, 0);
}
#elif __has_builtin(__builtin_amdgcn_mfma_f32_16x16x16_f16)
__device__ __forceinline__ f32x4 MFMA16(f16x4 a, f16x4 b, f32x4 c) {
    return __builtin_amdgcn_mfma_f32_16x16x16_f16(a, b, c, 0, 0, 0);
}
#else
__device__ __forceinline__ f32x4 MFMA16(f16x4 a, f16x4 b, f32x4 c) {
    f32x4 d;
    asm volatile("v_mfma_f32_16x16x16_f16 %0, %1, %2, %3"
                 : "=v"(d) : "v"(a), "v"(b), "v"(c));
    return d;
}
#endif

__device__ __forceinline__ float fast_rcp(float x)  { return __builtin_amdgcn_rcpf(x); }
__device__ __forceinline__ float fast_rsq(float x)  { return __builtin_amdgcn_rsqf(x); }
__device__ __forceinline__ float fast_exp2(float x) { return __builtin_amdgcn_exp2f(x); }

// butterfly sum over lanes {l, l^16, l^32, l^48} — VALU permlane on gfx950, no LDS
__device__ __forceinline__ float bfly16_32(float x) {
#if __has_builtin(__builtin_amdgcn_permlane16_swap) && __has_builtin(__builtin_amdgcn_permlane32_swap)
    unsigned u = __builtin_bit_cast(unsigned, x);
    auto p16 = __builtin_amdgcn_permlane16_swap(u, u, false, false);
    float s = __builtin_bit_cast(float, (unsigned)p16[0]) + __builtin_bit_cast(float, (unsigned)p16[1]);
    unsigned v = __builtin_bit_cast(unsigned, s);
    auto p32 = __builtin_amdgcn_permlane32_swap(v, v, false, false);
    return __builtin_bit_cast(float, (unsigned)p32[0]) + __builtin_bit_cast(float, (unsigned)p32[1]);
#else
    x += __shfl_xor(x, 16);
    x += __shfl_xor(x, 32);
    return x;
#endif
}

// gelu(t) ~= t * sigmoid(2 * t * (A + B t^2)); 2*log2(e) pre-folded into A,B
__device__ __forceinline__ float gelu_tanh(float t) {
    const float A2 = 0.79788456080286536f * 2.88539008177792681f;
    const float B2 = 0.03567740814183430f * 2.88539008177792681f;
    float u  = t * fmaf(t * t, B2, A2);
    float e  = fast_exp2(u);
    float r  = fast_rcp(e + 1.0f);
    return fmaf(-t, r, t);
}

__device__ __forceinline__ f16x4 pk4(float a, float b, float c, float d) {
    h2 lo = pkrtz(a, b), hi = pkrtz(c, d);
    f16x4 r; r[0] = lo[0]; r[1] = lo[1]; r[2] = hi[0]; r[3] = hi[1];
    return r;
}
__device__ __forceinline__ f32x4 ld4(const float* p) {
    float4 t = *(const float4*)p;
    f32x4 r; r[0] = t.x; r[1] = t.y; r[2] = t.z; r[3] = t.w;
    return r;
}
__device__ __forceinline__ h2 h2at(f16x8 v, int i) {   // i compile-time, 0..3
    h2 r; r[0] = v[2 * i]; r[1] = v[2 * i + 1]; return r;
}

// ---- workspace layout ----
// [0, 6400) h2  : 50 weight tiles of 64 lanes x 2 h2 (A-fragment, lane = A[row=l&15][k=(l>>4)*4+i])
//   tile 0 patchify, tile 1 decoder; per layer li (base 2+li*12):
//   j=0..2 qkv (q-tile pre-scaled by QS; qkv & w1 cols pre-scaled by LN gain)
//   j=3 out_w ; j=4..7 w1 ; j=8..11 w2
// [6400 h2 ..) f32: per layer 112 floats: 48 folded qkv bias, 64 folded w1 bias
#define WS_H2_COUNT 6400
#define WS_BIAS_FLOATS (NLAYER * 112)
#define WS_TOTAL_BYTES (WS_H2_COUNT * 4 + WS_BIAS_FLOATS * 4)
#define PREP_ITEMS (WS_H2_COUNT + WS_BIAS_FLOATS)

__global__ __launch_bounds__(512) void prep_weights(
    const float* __restrict__ patch_w, const float* __restrict__ dec_w,
    const float* __restrict__ qkv_w, const float* __restrict__ out_w,
    const float* __restrict__ mlp_w1, const float* __restrict__ mlp_w2,
    const float* __restrict__ ln1_g, const float* __restrict__ ln1_b,
    const float* __restrict__ ln2_g, const float* __restrict__ ln2_b,
    const float* __restrict__ qkv_b, const float* __restrict__ mlp_b1,
    h2* __restrict__ ws)
{
    int i = blockIdx.x * 512 + threadIdx.x;
    if (i >= PREP_ITEMS) return;
    if (i < WS_H2_COUNT) {
        int tile = i >> 7;
        int lane = (i >> 1) & 63;
        int p    = i & 1;
        int row  = lane & 15;
        int kb   = (lane >> 4) * 4 + 2 * p;
        float a, b;
        if (tile == 0)      { a = patch_w[row * 16 + kb];  b = patch_w[row * 16 + kb + 1]; }
        else if (tile == 1) { a = dec_w[kb * 16 + row];    b = dec_w[(kb + 1) * 16 + row]; }
        else {
            int t2 = tile - 2, li = t2 / 12, j = t2 % 12;
            const float* s;
            float g0 = 1.0f, g1v = 1.0f;
            if (j < 3) {
                s = qkv_w + li * 768 + (j * 16 + row) * 16 + kb;
                g0 = ln1_g[li * 16 + kb]; g1v = ln1_g[li * 16 + kb + 1];
                if (j == 0) { g0 *= QS; g1v *= QS; }
            } else if (j == 3) {
                s = out_w + li * 256 + row * 16 + kb;
            } else if (j < 8) {
                s = mlp_w1 + li * 1024 + ((j - 4) * 16 + row) * 16 + kb;
                g0 = ln2_g[li * 16 + kb]; g1v = ln2_g[li * 16 + kb + 1];
            } else {
                s = mlp_w2 + li * 1024 + row * 64 + (j - 8) * 16 + kb;
            }
            a = s[0] * g0; b = s[1] * g1v;
        }
        ws[i] = pkrtz(a, b);
    } else {
        int t = i - WS_H2_COUNT;
        int li = t / 112, r = t % 112;
        float* wbf = (float*)(ws + WS_H2_COUNT);
        float bv;
        if (r < 48) {
            const float* Wr = qkv_w + li * 768 + r * 16;
            const float* lb = ln1_b + li * 16;
            bv = qkv_b[li * 48 + r];
            for (int d = 0; d < 16; ++d) bv = fmaf(Wr[d], lb[d], bv);
            if (r < 16) bv *= QS;
        } else {
            int j = r - 48;
            const float* Wr = mlp_w1 + li * 1024 + j * 16;
            const float* lb = ln2_b + li * 16;
            bv = mlp_b1[li * 64 + j];
            for (int d = 0; d < 16; ++d) bv = fmaf(Wr[d], lb[d], bv);
        }
        wbf[li * 112 + r] = bv;
    }
}

__global__ __launch_bounds__(NTHREADS, 3) void ae_fwd(
    const float* __restrict__ x,
    const float* __restrict__ patch_b, const float* __restrict__ pos_embed,
    const h2*    __restrict__ wp, const float* __restrict__ wb,
    const float* __restrict__ out_b, const float* __restrict__ mlp_b2,
    const float* __restrict__ lnf_g, const float* __restrict__ lnf_b,
    const float* __restrict__ dec_b,
    float* __restrict__ out_y, float* __restrict__ out_z)
{
    __shared__ float smem[SMEM_DW];
    const int lane = threadIdx.x;    // 0..63, one wave
    const int col  = lane & 15;      // token-within-tile (MFMA col)
    const int g16  = lane >> 4;      // 0..3: k-group AND head index
    const int fb   = g16 * 4;        // this lane's feature base

    // ---- stage x (coalesced float4); same wave consumes it, no barrier ----
    {
        const float4* xg = (const float4*)(x + (long long)blockIdx.x * (EPB * LIN));
        float4* xs = (float4*)smem;
        #pragma unroll
        for (int i = 0; i < 9; ++i) {
            int idx = lane + i * 64;
            if (idx < (EPB * LIN) / 4) xs[idx] = xg[idx];
        }
    }

    // ---- per-tile token -> (element, seq) ----
    int elemL[9], sIdx[9];
    #pragma unroll
    for (int t = 0; t < 9; ++t) {
        int T = t * 16 + col;                // 0..143
        int e = (T * 57) >> 10;              // floor(T/18), exact for T<504
        elemL[t] = e;
        sIdx[t]  = T - 18 * e;
    }

    const f16x4* wfrag = (const f16x4*)wp;
    const f16x4 wpatch = wfrag[lane];

    // ---- patchify via MFMA (reads staged x) ----
    float hacc[9][4];
    {
        const float4 pb = *(const float4*)(patch_b + fb);
        #pragma unroll
        for (int t = 0; t < 9; ++t) {
            float xv[4];
            #pragma unroll
            for (int r = 0; r < 4; ++r) {
                int loc = sIdx[t] * 16 - 7 + fb + r;
                xv[r] = (loc >= 0 && loc < LIN) ? smem[elemL[t] * LIN + loc] : 0.0f;
            }
            f16x4 xb = pk4(xv[0], xv[1], xv[2], xv[3]);
            const float4 pe = *(const float4*)(pos_embed + sIdx[t] * DM + fb);
            f32x4 c; c[0] = pb.x + pe.x; c[1] = pb.y + pe.y; c[2] = pb.z + pe.z; c[3] = pb.w + pe.w;
            c = MFMA16(wpatch, xb, c);
            #pragma unroll
            for (int r = 0; r < 4; ++r) hacc[t][r] = c[r];
        }
    }

    #pragma unroll 1
    for (int li = 0; li < NLAYER; ++li) {
        const f16x4* wl = wfrag + (2 + li * 12) * 64 + lane;
        const float* wbL = wb + li * 112;

        // ---- phase A: LN1 (affine folded) + QKV + K/V publish (no barrier) ----
        h2 qp[9][2];
        {
            const f32x4 bq  = ld4(wbL + fb);
            const f32x4 bk  = ld4(wbL + 16 + fb);
            const f32x4 bvx = ld4(wbL + 32 + fb);
            const f16x4 wq = wl[0], wk = wl[64], wvw = wl[128];
            #pragma unroll
            for (int t = 0; t < 9; ++t) {
                float a0 = hacc[t][0], a1 = hacc[t][1], a2 = hacc[t][2], a3 = hacc[t][3];
                float sm = bfly16_32(a0 + a1 + a2 + a3);
                float qq = bfly16_32(fmaf(a0, a0, fmaf(a1, a1, fmaf(a2, a2, a3 * a3))));
                float mean = sm * (1.0f / 16.0f);
                float var  = fmaxf(fmaf(mean, -mean, qq * (1.0f / 16.0f)), 0.0f);
                float inv  = fast_rsq(var + EPSF);
                float mi   = mean * inv;
                f16x4 xb = pk4(fmaf(a0, inv, -mi), fmaf(a1, inv, -mi),
                               fmaf(a2, inv, -mi), fmaf(a3, inv, -mi));
                f32x4 aq = MFMA16(wq,  xb, bq);
                f32x4 ak = MFMA16(wk,  xb, bk);
                f32x4 av = MFMA16(wvw, xb, bvx);
                qp[t][0] = pkrtz(aq[0], aq[1]);
                qp[t][1] = pkrtz(aq[2], aq[3]);
                // K: row (e*4+g16), stride 36 dw, entry s*2 (b64, conflict-free)
                *(f16x4*)(smem + (elemL[t] * 4 + g16) * 36 + sIdx[t] * 2) =
                    pk4(ak[0], ak[1], ak[2], ak[3]);
                // V: token stride 10 dw (bank base 10*T walks all 8 phases), head slot g16*2
                *(f16x4*)(smem + VOFF_DW + (elemL[t] * 18 + sIdx[t]) * 10 + g16 * 2) =
                    pk4(av[0], av[1], av[2], av[3]);
            }
        }

        // ---- phase B: attention (softmax lane-local) + out-proj ----
        {
            const float4 ob4 = *(const float4*)(out_b + li * DM + fb);
            const f16x4 wo = wl[192];
            #pragma unroll
            for (int t = 0; t < 9; ++t) {
                const float* Kb = smem + (elemL[t] * 4 + g16) * 36;
                float sc[SEQ]; float ssum = 0.0f;
                #pragma unroll
                for (int jp = 0; jp < 9; ++jp) {
                    f16x8 k2 = *(const f16x8*)(Kb + jp * 4);
                    float s0 = fdot2(qp[t][1], h2at(k2, 1), fdot2(qp[t][0], h2at(k2, 0), 0.0f));
                    float s1 = fdot2(qp[t][1], h2at(k2, 3), fdot2(qp[t][0], h2at(k2, 2), 0.0f));
                    float w0 = fast_exp2(s0), w1 = fast_exp2(s1);
                    sc[2 * jp] = w0; sc[2 * jp + 1] = w1;
                    ssum += w0 + w1;
                }
                float inv = fast_rcp(ssum);
                const float* vbase = smem + VOFF_DW + elemL[t] * 180 + g16 * 2;
                float o0 = 0.f, o1 = 0.f, o2 = 0.f, o3 = 0.f;
                #pragma unroll
                for (int j = 0; j < SEQ; ++j) {
                    f16x4 vj = *(const f16x4*)(vbase + j * 10);
                    float w = sc[j];
                    o0 = fmaf(w, (float)vj[0], o0);   // v_fma_mix_f32
                    o1 = fmaf(w, (float)vj[1], o1);
                    o2 = fmaf(w, (float)vj[2], o2);
                    o3 = fmaf(w, (float)vj[3], o3);
                }
                f16x4 obf = pk4(o0 * inv, o1 * inv, o2 * inv, o3 * inv);
                f32x4 oa; oa[0] = ob4.x; oa[1] = ob4.y; oa[2] = ob4.z; oa[3] = ob4.w;
                oa = MFMA16(wo, obf, oa);
                #pragma unroll
                for (int r = 0; r < 4; ++r) hacc[t][r] += oa[r];
            }
        }

        // ---- phase C: LN2 (affine folded) + MLP ----
        {
            f32x4 b1r[4]; f16x4 w1c[4], w2c[4];
            #pragma unroll
            for (int c = 0; c < 4; ++c) {
                b1r[c] = ld4(wbL + 48 + c * 16 + fb);
                w1c[c] = wl[(4 + c) * 64];
                w2c[c] = wl[(8 + c) * 64];
            }
            const f32x4 b2r = ld4(mlp_b2 + li * DM + fb);
            #pragma unroll
            for (int t = 0; t < 9; ++t) {
                float a0 = hacc[t][0], a1 = hacc[t][1], a2 = hacc[t][2], a3 = hacc[t][3];
                float sm = bfly16_32(a0 + a1 + a2 + a3);
                float qq = bfly16_32(fmaf(a0, a0, fmaf(a1, a1, fmaf(a2, a2, a3 * a3))));
                float mean = sm * (1.0f / 16.0f);
                float var  = fmaxf(fmaf(mean, -mean, qq * (1.0f / 16.0f)), 0.0f);
                float inv  = fast_rsq(var + EPSF);
                float mi   = mean * inv;
                f16x4 xb2 = pk4(fmaf(a0, inv, -mi), fmaf(a1, inv, -mi),
                                fmaf(a2, inv, -mi), fmaf(a3, inv, -mi));
                f32x4 acc2 = b2r;
                #pragma unroll
                for (int c = 0; c < 4; ++c) {
                    f32x4 m1 = MFMA16(w1c[c], xb2, b1r[c]);
                    f16x4 gb = pk4(gelu_tanh(m1[0]), gelu_tanh(m1[1]),
                                   gelu_tanh(m1[2]), gelu_tanh(m1[3]));
                    acc2 = MFMA16(w2c[c], gb, acc2);
                }
                #pragma unroll
                for (int r = 0; r < 4; ++r) hacc[t][r] += acc2[r];
            }
        }
    }

    // ---- final LN + z + decoder (MFMA) + y ----
    const f16x4 wdec = wfrag[64 + lane];
    const float4 gf = *(const float4*)(lnf_g + fb);
    const float4 bf = *(const float4*)(lnf_b + fb);
    const float db0 = dec_b[0];
    #pragma unroll
    for (int t = 0; t < 9; ++t) {
        float a0 = hacc[t][0], a1 = hacc[t][1], a2 = hacc[t][2], a3 = hacc[t][3];
        float sm = bfly16_32(a0 + a1 + a2 + a3);
        float qq = bfly16_32(fmaf(a0, a0, fmaf(a1, a1, fmaf(a2, a2, a3 * a3))));
        float mean = sm * (1.0f / 16.0f);
        float var  = fmaxf(fmaf(mean, -mean, qq * (1.0f / 16.0f)), 0.0f);
        float inv  = fast_rsq(var + EPSF);
        float mi   = mean * inv;
        float f0 = fmaf(fmaf(a0, inv, -mi), gf.x, bf.x);
        float f1 = fmaf(fmaf(a1, inv, -mi), gf.y, bf.y);
        float f2 = fmaf(fmaf(a2, inv, -mi), gf.z, bf.z);
        float f3 = fmaf(fmaf(a3, inv, -mi), gf.w, bf.w);

        long long eg = (long long)blockIdx.x * EPB + elemL[t];
        float* zb = out_z + eg * (DM * SEQ) + sIdx[t];
        zb[(fb + 0) * SEQ] = f0; zb[(fb + 1) * SEQ] = f1;
        zb[(fb + 2) * SEQ] = f2; zb[(fb + 3) * SEQ] = f3;

        f16x4 hb = pk4(f0, f1, f2, f3);
        f32x4 y4; y4[0] = db0; y4[1] = db0; y4[2] = db0; y4[3] = db0;
        y4 = MFMA16(wdec, hb, y4);
        float* yb = out_y + eg * LIN;
        int p0 = sIdx[t] * 16 + fb - 7;
        #pragma unroll
        for (int r = 0; r < 4; ++r) {
            int p = p0 + r;
            if (p >= 0 && p < LIN) yb[p] = y4[r];
        }
    }
}

// ---------------- fp32 fallback (used only if ws_size is too small) ----------------
#define EPB_F 14
#define NT_F  252
__global__ __launch_bounds__(NT_F) void ae_fwd_f32(
    const float* __restrict__ x,
    const float* __restrict__ patch_w, const float* __restrict__ patch_b,
    const float* __restrict__ pos_embed,
    const float* __restrict__ ln1_g, const float* __restrict__ ln1_b,
    const float* __restrict__ qkv_w, const float* __restrict__ qkv_b,
    const float* __restrict__ out_w, const float* __restrict__ out_b,
    const float* __restrict__ ln2_g, const float* __restrict__ ln2_b,
    const float* __restrict__ mlp_w1, const float* __restrict__ mlp_b1,
    const float* __restrict__ mlp_w2, const float* __restrict__ mlp_b2,
    const float* __restrict__ lnf_g, const float* __restrict__ lnf_b,
    const float* __restrict__ dec_w, const float* __restrict__ dec_b,
    float* __restrict__ out_y, float* __restrict__ out_z)
{
    __shared__ float s_kv[EPB_F * 580];
    const int tid = threadIdx.x;
    const int e   = tid / SEQ;
    const int s   = tid - e * SEQ;
    const long long b = (long long)blockIdx.x * EPB_F + e;
    const bool valid = (b < NB);
    {
        const long long base = (long long)blockIdx.x * (EPB_F * LIN);
        const long long lim  = (long long)NB * LIN - 1;
        for (int i = tid; i < EPB_F * LIN; i += NT_F) {
            long long gi = base + i;
            if (gi > lim) gi = lim;
            s_kv[i] = x[gi];
        }
    }
    __syncthreads();
    float xv[16];
    {
        const float* xe = &s_kv[e * LIN];
        #pragma unroll
        for (int k = 0; k < 16; ++k) {
            int idx = s * 16 - 7 + k;
            xv[k] = (idx >= 0 && idx < LIN) ? xe[idx] : 0.0f;
        }
    }
    float h[DM];
    #pragma unroll
    for (int d = 0; d < DM; ++d) {
        float acc = patch_b[d] + pos_embed[s * DM + d];
        #pragma unroll
        for (int k = 0; k < 16; ++k) acc = fmaf(xv[k], patch_w[d * 16 + k], acc);
        h[d] = acc;
    }
    #pragma unroll 1
    for (int li = 0; li < NLAYER; ++li) {
        float xn[DM];
        {
            float m = 0.f;
            #pragma unroll
            for (int d = 0; d < DM; ++d) m += h[d];
            m *= (1.0f / DM);
            float v = 0.f;
            #pragma unroll
            for (int d = 0; d < DM; ++d) { float t = h[d] - m; v = fmaf(t, t, v); }
            v *= (1.0f / DM);
            float inv = fast_rsq(v + EPSF);
            #pragma unroll
            for (int d = 0; d < DM; ++d) xn[d] = (h[d] - m) * inv * ln1_g[li * DM + d] + ln1_b[li * DM + d];
        }
        float q[DM], kk[DM], vv[DM];
        {
            const float* W  = qkv_w + li * 48 * DM;
            const float* Wb = qkv_b + li * 48;
            #pragma unroll
            for (int j = 0; j < DM; ++j) {
                float aq = Wb[j], ak = Wb[DM + j], av = Wb[2 * DM + j];
                #pragma unroll
                for (int d = 0; d < DM; ++d) {
                    float xd = xn[d];
                    aq = fmaf(xd, W[j * DM + d], aq);
                    ak = fmaf(xd, W[(DM + j) * DM + d], ak);
                    av = fmaf(xd, W[(2 * DM + j) * DM + d], av);
                }
                q[j] = aq; kk[j] = ak; vv[j] = av;
            }
        }
        __syncthreads();
        {
            float* kb = &s_kv[e * 580];
            float* vb = kb + SEQ * DM;
            #pragma unroll
            for (int j = 0; j < DM; ++j) kb[s * DM + j] = kk[j];
            #pragma unroll
            for (int j = 0; j < DM; ++j) vb[s * DM + j] = vv[j];
        }
        __syncthreads();
        float o[DM];
        {
            const float* kb = &s_kv[e * 580];
            const float* vb = kb + SEQ * DM;
            #pragma unroll
            for (int hh = 0; hh < NH; ++hh) {
                const float qscale = 0.5f * 1.44269504088896341f;
                const float q0 = q[hh * 4] * qscale, q1 = q[hh * 4 + 1] * qscale;
                const float q2 = q[hh * 4 + 2] * qscale, q3 = q[hh * 4 + 3] * qscale;
                float sc[SEQ];
                float ssum = 0.f;
                #pragma unroll
                for (int j = 0; j < SEQ; ++j) {
                    const float4 kj = *(const float4*)(kb + j * DM + hh * 4);
                    float t = fmaf(q0, kj.x, fmaf(q1, kj.y, fmaf(q2, kj.z, q3 * kj.w)));
                    float w = fast_exp2(t);
                    sc[j] = w; ssum += w;
                }
                const float inv = fast_rcp(ssum);
                float a0 = 0.f, a1 = 0.f, a2 = 0.f, a3 = 0.f;
                #pragma unroll
                for (int j = 0; j < SEQ; ++j) {
                    const float4 vj = *(const float4*)(vb + j * DM + hh * 4);
                    const float w = sc[j] * inv;
                    a0 = fmaf(w, vj.x, a0); a1 = fmaf(w, vj.y, a1);
                    a2 = fmaf(w, vj.z, a2); a3 = fmaf(w, vj.w, a3);
                }
                o[hh * 4] = a0; o[hh * 4 + 1] = a1; o[hh * 4 + 2] = a2; o[hh * 4 + 3] = a3;
            }
        }
        {
            const float* W  = out_w + li * DM * DM;
            #pragma unroll
            for (int d = 0; d < DM; ++d) {
                float acc = out_b[li * DM + d];
                #pragma unroll
                for (int d2 = 0; d2 < DM; ++d2) acc = fmaf(o[d2], W[d * DM + d2], acc);
                h[d] += acc;
            }
        }
        float xn2[DM];
        {
            float m = 0.f;
            #pragma unroll
            for (int d = 0; d < DM; ++d) m += h[d];
            m *= (1.0f / DM);
            float v = 0.f;
            #pragma unroll
            for (int d = 0; d < DM; ++d) { float t = h[d] - m; v = fmaf(t, t, v); }
            v *= (1.0f / DM);
            float inv = fast_rsq(v + EPSF);
            #pragma unroll
            for (int d = 0; d < DM; ++d) xn2[d] = (h[d] - m) * inv * ln2_g[li * DM + d] + ln2_b[li * DM + d];
        }
        {
            const float* W1 = mlp_w1 + li * HID * DM;
            const float* W2 = mlp_w2 + li * DM * HID;
            float acc2[DM];
            #pragma unroll
            for (int d = 0; d < DM; ++d) acc2[d] = mlp_b2[li * DM + d];
            #pragma unroll 2
            for (int j = 0; j < HID; ++j) {
                float t = mlp_b1[li * HID + j];
                #pragma unroll
                for (int d = 0; d < DM; ++d) t = fmaf(xn2[d], W1[j * DM + d], t);
                float g = gelu_tanh(t);
                #pragma unroll
                for (int d = 0; d < DM; ++d) acc2[d] = fmaf(g, W2[d * HID + j], acc2[d]);
            }
            #pragma unroll
            for (int d = 0; d < DM; ++d) h[d] += acc2[d];
        }
    }
    {
        float m = 0.f;
        #pragma unroll
        for (int d = 0; d < DM; ++d) m += h[d];
        m *= (1.0f / DM);
        float v = 0.f;
        #pragma unroll
        for (int d = 0; d < DM; ++d) { float t = h[d] - m; v = fmaf(t, t, v); }
        v *= (1.0f / DM);
        float inv = fast_rsq(v + EPSF);
        #pragma unroll
        for (int d = 0; d < DM; ++d) h[d] = (h[d] - m) * inv * lnf_g[d] + lnf_b[d];
    }
    if (valid) {
        float* zb = out_z + b * (DM * SEQ);
        #pragma unroll
        for (int d = 0; d < DM; ++d) zb[d * SEQ + s] = h[d];
        float* yb = out_y + b * LIN;
        const float db0 = dec_b[0];
        #pragma unroll
        for (int k = 0; k < 16; ++k) {
            int t = s * 16 + k - 7;
            if (t >= 0 && t < LIN) {
                float acc = db0;
                #pragma unroll
                for (int d = 0; d < DM; ++d) acc = fmaf(h[d], dec_w[d * 16 + k], acc);
                yb[t] = acc;
            }
        }
    }
}

extern "C" void kernel_launch(void* const* d_in, const int* in_sizes, int n_in,
                              void* d_out, int out_size, void* d_ws, size_t ws_size,
                              hipStream_t stream) {
    const float* x        = (const float*)d_in[0];
    const float* patch_w  = (const float*)d_in[1];
    const float* patch_b  = (const float*)d_in[2];
    const float* pos_e    = (const float*)d_in[3];
    const float* ln1_g    = (const float*)d_in[4];
    const float* ln1_b    = (const float*)d_in[5];
    const float* qkv_w    = (const float*)d_in[6];
    const float* qkv_b    = (const float*)d_in[7];
    const float* out_w    = (const float*)d_in[8];
    const float* out_b    = (const float*)d_in[9];
    const float* ln2_g    = (const float*)d_in[10];
    const float* ln2_b    = (const float*)d_in[11];
    const float* mlp_w1   = (const float*)d_in[12];
    const float* mlp_b1   = (const float*)d_in[13];
    const float* mlp_w2   = (const float*)d_in[14];
    const float* mlp_b2   = (const float*)d_in[15];
    const float* lnf_g    = (const float*)d_in[16];
    const float* lnf_b    = (const float*)d_in[17];
    const float* dec_w    = (const float*)d_in[18];
    const float* dec_b    = (const float*)d_in[19];

    float* out_y = (float*)d_out;                       // (B,1,274) first
    float* out_z = out_y + (long long)NB * LIN;         // then (B,16,18)

    if (ws_size >= WS_TOTAL_BYTES) {
        h2* wsp = (h2*)d_ws;
        const float* wbp = (const float*)(wsp + WS_H2_COUNT);
        prep_weights<<<(PREP_ITEMS + 511) / 512, 512, 0, stream>>>(
            patch_w, dec_w, qkv_w, out_w, mlp_w1, mlp_w2,
            ln1_g, ln1_b, ln2_g, ln2_b, qkv_b, mlp_b1, wsp);
        ae_fwd<<<NB / EPB, NTHREADS, 0, stream>>>(
            x, patch_b, pos_e, wsp, wbp,
            out_b, mlp_b2, lnf_g, lnf_b, dec_b, out_y, out_z);
    } else {
        const int grid = (NB + EPB_F - 1) / EPB_F;
        ae_fwd_f32<<<grid, NT_F, 0, stream>>>(
            x, patch_w, patch_b, pos_e, ln1_g, ln1_b, qkv_w, qkv_b,
            out_w, out_b, ln2_g, ln2_b, mlp_w1, mlp_b1, mlp_w2, mlp_b2,
            lnf_g, lnf_b, dec_w, dec_b, out_y, out_z);
    }
}